// Round 6
// baseline (435.187 us; speedup 1.0000x reference)
//
#include <hip/hip_runtime.h>
#include <hip/hip_fp16.h>

typedef unsigned int uint;
typedef unsigned short ushort;

typedef __attribute__((ext_vector_type(8))) _Float16 f16x8;
typedef __attribute__((ext_vector_type(4))) float f32x4;

#define TOK 256
#define OUTF 11008
#define INF 4096
#define BN 64
#define NT2 172  // OUTF / BN

__device__ __constant__ float NF4_TBL[16] = {
    -1.0f, -0.6961928009986877f, -0.5250730514526367f, -0.39491748809814453f,
    -0.28444138169288635f, -0.18477343022823334f, -0.09105003625154495f, 0.0f,
    0.07958029955625534f, 0.16093020141124725f, 0.24611230194568634f,
    0.33791524171829224f, 0.44070982933044434f, 0.5626170039176941f,
    0.7229568362236023f, 1.0f};

__device__ __forceinline__ ushort f2h(float f) {
  return __half_as_ushort(__float2half(f));
}

// kernel 1 (fused prep): pack q int32->nibbles; x fp32->f16; lora_B fp32 [OUTF,16]->f16 [OUTF,64] padded
__global__ void prep_kernel(const int4* __restrict__ qc4, uint* __restrict__ pk,
                            const float4* __restrict__ x4, ushort4* __restrict__ xh4,
                            const float4* __restrict__ lB4, ushort4* __restrict__ lBh4) {
  const int stride = gridDim.x * blockDim.x;
  const int t0 = blockIdx.x * blockDim.x + threadIdx.x;
  for (int d = t0; d < OUTF * INF / 8; d += stride) {
    int4 a = qc4[2 * d];
    int4 b = qc4[2 * d + 1];
    pk[d] = (uint)(a.x & 15) | ((uint)(a.y & 15) << 4) | ((uint)(a.z & 15) << 8) |
            ((uint)(a.w & 15) << 12) | ((uint)(b.x & 15) << 16) | ((uint)(b.y & 15) << 20) |
            ((uint)(b.z & 15) << 24) | ((uint)(b.w & 15) << 28);
  }
  for (int i = t0; i < TOK * INF / 4; i += stride) {
    float4 v = x4[i];
    ushort4 o;
    o.x = f2h(v.x); o.y = f2h(v.y); o.z = f2h(v.z); o.w = f2h(v.w);
    xh4[i] = o;
  }
  for (int i = t0; i < OUTF * 16; i += stride) {
    int n = i >> 4, jq = i & 15;
    ushort4 o = {0, 0, 0, 0};
    if (jq < 4) {
      float4 v = lB4[n * 4 + jq];
      o.x = f2h(v.x); o.y = f2h(v.y); o.z = f2h(v.z); o.w = f2h(v.w);
    }
    lBh4[i] = o;
  }
}

// kernel 2: xa2[m][j] = f16( 2 * sum_k x[m][k]*lora_A[j][k] ), [TOK,64] zero-padded
__global__ __launch_bounds__(1024)
void xa_kernel(const float* __restrict__ x, const float* __restrict__ lA,
               ushort* __restrict__ xa2) {
  const int m = blockIdx.x;
  const int t = threadIdx.x;
  const float4* x4 = (const float4*)(x + (size_t)m * INF);
  const float4* lA4 = (const float4*)lA;
  float4 xv = x4[t];
  float acc[16];
#pragma unroll
  for (int j = 0; j < 16; ++j) {
    float4 a = lA4[j * (INF / 4) + t];
    acc[j] = xv.x * a.x + xv.y * a.y + xv.z * a.z + xv.w * a.w;
  }
#pragma unroll
  for (int j = 0; j < 16; ++j)
#pragma unroll
    for (int s = 32; s > 0; s >>= 1) acc[j] += __shfl_xor(acc[j], s, 64);
  __shared__ float red[16][16];
  const int w = t >> 6, l = t & 63;
  if (l == 0) {
#pragma unroll
    for (int j = 0; j < 16; ++j) red[w][j] = acc[j];
  }
  __syncthreads();
  if (t < 64) {
    ushort v = 0;
    if (t < 16) {
      float s = 0.f;
#pragma unroll
      for (int w2 = 0; w2 < 16; ++w2) s += red[w2][t];
      v = f2h(2.0f * s);
    }
    xa2[m * 64 + t] = v;
  }
}

// kernel 3: BARRIER-FREE fused dequant GEMM. Each wave owns 64 rows x 64 cols.
// A-frags direct from L2-hot xh; B dequant in-register from packed nibbles via
// LDS pair-table. q prefetched 2 macro-steps (128 k) ahead, A 1 substep ahead,
// all prefetches UNCONDITIONAL (overreads land inside adjacent ws buffers).
__global__ __launch_bounds__(256, 2)
void gemm_kernel(const uint* __restrict__ pk, const float* __restrict__ am,
                 const ushort* __restrict__ xh, const ushort* __restrict__ lBh,
                 const ushort* __restrict__ xa2, float* __restrict__ dest, int nst) {
  __shared__ __half2 tbl[256];  // byte -> (nf4[lo], nf4[hi]) unscaled

  const int tid = threadIdx.x;
  const int w = tid >> 6;
  const int l = tid & 63;
  const int chunk = l >> 4;  // 0..3
  const int rlo = l & 15;
  const int split = blockIdx.x / NT2;
  const int ntile = blockIdx.x - split * NT2;
  const int n0 = ntile * BN;
  const int k0 = split * nst * 64;

  tbl[tid & 255] = __halves2half2(__float2half(NF4_TBL[tid & 15]),
                                  __float2half(NF4_TBL[(tid >> 4) & 15]));
  __syncthreads();  // the ONLY barrier

  // per-lane A base pointers (16B frag per mt per substep)
  const ushort* aptr[4];
#pragma unroll
  for (int mt = 0; mt < 4; ++mt)
    aptr[mt] = xh + (size_t)(w * 64 + mt * 16 + rlo) * INF + chunk * 8 + k0;

  int col[4];
  const char* qp[4];
  const float* amp[4];
#pragma unroll
  for (int nt = 0; nt < 4; ++nt) {
    col[nt] = n0 + nt * 16 + rlo;
    qp[nt] = (const char*)pk + (size_t)col[nt] * (INF / 2) + (k0 >> 1) + chunk * 4;
    amp[nt] = am + (size_t)col[nt] * 64 + (k0 >> 6);
  }

  f32x4 acc[4][4];
#pragma unroll
  for (int mt = 0; mt < 4; ++mt)
#pragma unroll
    for (int nt = 0; nt < 4; ++nt) acc[mt][nt] = (f32x4){0.f, 0.f, 0.f, 0.f};

  // q pipeline: 2 macro-stages (parity), 8 dwords + 4 amax each
  uint qd[2][8];
  float ax[2][4];
#pragma unroll
  for (int p = 0; p < 2; ++p)
#pragma unroll
    for (int nt = 0; nt < 4; ++nt) {
      qd[p][nt * 2 + 0] = *(const uint*)(qp[nt] + p * 32);
      qd[p][nt * 2 + 1] = *(const uint*)(qp[nt] + p * 32 + 16);
      ax[p][nt] = amp[nt][p];
    }
  // A pipeline: current substep frags
  f16x8 aC[4];
#pragma unroll
  for (int mt = 0; mt < 4; ++mt) aC[mt] = *(const f16x8*)(aptr[mt]);

#pragma unroll 2
  for (int s = 0; s < nst; ++s) {
    const int par = s & 1;
#pragma unroll
    for (int sub = 0; sub < 2; ++sub) {
      // unconditional A prefetch for next substep (overread ok: spills into lBh)
      const int kn = (s * 2 + sub + 1) * 32;
      f16x8 aN[4];
#pragma unroll
      for (int mt = 0; mt < 4; ++mt) aN[mt] = *(const f16x8*)(aptr[mt] + kn);
      // dequant B frags from the 2-stage q pipeline
      f16x8 b[4];
#pragma unroll
      for (int nt = 0; nt < 4; ++nt) {
        uint dw = qd[par][nt * 2 + sub];
        __half2 ax2 = __float2half2_rn(ax[par][nt]);
        union { __half2 h[4]; f16x8 v; } u;
        u.h[0] = __hmul2(tbl[dw & 255], ax2);
        u.h[1] = __hmul2(tbl[(dw >> 8) & 255], ax2);
        u.h[2] = __hmul2(tbl[(dw >> 16) & 255], ax2);
        u.h[3] = __hmul2(tbl[dw >> 24], ax2);
        b[nt] = u.v;
      }
#pragma unroll
      for (int mt = 0; mt < 4; ++mt)
#pragma unroll
        for (int nt = 0; nt < 4; ++nt)
          acc[mt][nt] = __builtin_amdgcn_mfma_f32_16x16x32_f16(aC[mt], b[nt], acc[mt][nt], 0, 0, 0);
#pragma unroll
      for (int mt = 0; mt < 4; ++mt) aC[mt] = aN[mt];
    }
    // unconditional q prefetch for macro s+2 (stays inside pk for all splits)
    const int am_i = (s + 2 < nst) ? (s + 2) : 0;  // clamp amax only (avoids d_in tail OOB)
#pragma unroll
    for (int nt = 0; nt < 4; ++nt) {
      qd[par][nt * 2 + 0] = *(const uint*)(qp[nt] + (s + 2) * 32);
      qd[par][nt * 2 + 1] = *(const uint*)(qp[nt] + (s + 2) * 32 + 16);
      ax[par][nt] = amp[nt][am_i];
    }
  }

  if (split == 0) {
    // lora K-extension: k in [0,32) (rank 16 + zero pad); direct register frags
    f16x8 a_l[4], b_l[4];
#pragma unroll
    for (int mt = 0; mt < 4; ++mt)
      a_l[mt] = *(const f16x8*)(xa2 + (size_t)(w * 64 + mt * 16 + rlo) * 64 + chunk * 8);
#pragma unroll
    for (int nt = 0; nt < 4; ++nt)
      b_l[nt] = *(const f16x8*)(lBh + (size_t)col[nt] * 64 + chunk * 8);
#pragma unroll
    for (int mt = 0; mt < 4; ++mt)
#pragma unroll
      for (int nt = 0; nt < 4; ++nt)
        acc[mt][nt] = __builtin_amdgcn_mfma_f32_16x16x32_f16(a_l[mt], b_l[nt], acc[mt][nt], 0, 0, 0);
  }

  // epilogue: C/D layout col=lane&15, row=(lane>>4)*4+reg; each split owns a slice
  float* dst = dest + (size_t)split * TOK * OUTF;
#pragma unroll
  for (int mt = 0; mt < 4; ++mt) {
#pragma unroll
    for (int nt = 0; nt < 4; ++nt) {
      int c = col[nt];
#pragma unroll
      for (int r = 0; r < 4; ++r) {
        int row = w * 64 + mt * 16 + chunk * 4 + r;
        dst[(size_t)row * OUTF + c] = acc[mt][nt][r];
      }
    }
  }
}

// kernel 4: sum K-split partials -> out
__global__ void reduce_kernel(const float4* __restrict__ part, float4* __restrict__ out,
                              int ks) {
  const int QN = TOK * OUTF / 4;
  int i = blockIdx.x * blockDim.x + threadIdx.x;
  if (i < QN) {
    float4 s = part[i];
    for (int s2 = 1; s2 < ks; ++s2) {
      float4 p = part[(size_t)s2 * QN + i];
      s.x += p.x; s.y += p.y; s.z += p.z; s.w += p.w;
    }
    out[i] = s;
  }
}

extern "C" void kernel_launch(void* const* d_in, const int* in_sizes, int n_in,
                              void* d_out, int out_size, void* d_ws, size_t ws_size,
                              hipStream_t stream) {
  const float* x = (const float*)d_in[0];
  const int* qc = (const int*)d_in[1];
  const float* am = (const float*)d_in[2];
  const float* lA = (const float*)d_in[3];
  const float* lB = (const float*)d_in[4];
  float* out = (float*)d_out;

  const size_t off_lB = (size_t)TOK * INF * 2;             // 2.10 MB
  const size_t off_xa2 = off_lB + (size_t)OUTF * 64 * 2;   // +1.41 MB
  const size_t off_pk = off_xa2 + (size_t)TOK * 64 * 2;    // +32 KB  = 3,538,944
  const size_t off_part = off_pk + (size_t)OUTF * INF / 2; // +22.5 MB = 26,083,328
  const size_t part_bytes = (size_t)TOK * OUTF * 4;        // 11.27 MB per split

  ushort* xh = (ushort*)d_ws;
  ushort* lBh = (ushort*)((char*)d_ws + off_lB);
  ushort* xa2 = (ushort*)((char*)d_ws + off_xa2);
  uint* pk = (uint*)((char*)d_ws + off_pk);
  float* part = (float*)((char*)d_ws + off_part);

  int ks = 1;
  if (ws_size >= off_part + 4 * part_bytes) ks = 4;       // ws ~688 MB observed -> ks=4
  else if (ws_size >= off_part + 2 * part_bytes) ks = 2;
  float* dest = (ks == 1) ? out : part;

  prep_kernel<<<4096, 256, 0, stream>>>((const int4*)qc, pk, (const float4*)x,
                                        (ushort4*)xh, (const float4*)lB, (ushort4*)lBh);
  xa_kernel<<<TOK, 1024, 0, stream>>>(x, lA, xa2);
  gemm_kernel<<<NT2 * ks, 256, 0, stream>>>(pk, am, xh, lBh, xa2, dest, 64 / ks);
  if (ks > 1)
    reduce_kernel<<<(TOK * OUTF / 4 + 255) / 256, 256, 0, stream>>>((const float4*)part,
                                                                    (float4*)out, ks);
}

// Round 7
// 386.505 us; speedup vs baseline: 1.1260x; 1.1260x over previous
//
#include <hip/hip_runtime.h>
#include <hip/hip_fp16.h>

typedef unsigned int uint;
typedef unsigned short ushort;

typedef __attribute__((ext_vector_type(8))) _Float16 f16x8;
typedef __attribute__((ext_vector_type(4))) float f32x4;

#define TOK 256
#define OUTF 11008
#define INF 4096
#define BM 256
#define BN 64
#define NT2 172  // OUTF / BN

__device__ __constant__ float NF4_TBL[16] = {
    -1.0f, -0.6961928009986877f, -0.5250730514526367f, -0.39491748809814453f,
    -0.28444138169288635f, -0.18477343022823334f, -0.09105003625154495f, 0.0f,
    0.07958029955625534f, 0.16093020141124725f, 0.24611230194568634f,
    0.33791524171829224f, 0.44070982933044434f, 0.5626170039176941f,
    0.7229568362236023f, 1.0f};

__device__ __forceinline__ ushort f2h(float f) {
  return __half_as_ushort(__float2half(f));
}

// async global->LDS, 16B per lane; lds base wave-uniform + lane*16
__device__ __forceinline__ void async_cp16(const void* g, void* l) {
  __builtin_amdgcn_global_load_lds(
      (const __attribute__((address_space(1))) uint*)g,
      (__attribute__((address_space(3))) uint*)l, 16, 0, 0);
}

// kernel 1 (fused prep): pack q int32->nibbles; x fp32->f16; lora_B fp32 [OUTF,16]->f16 [OUTF,64] padded
__global__ void prep_kernel(const int4* __restrict__ qc4, uint* __restrict__ pk,
                            const float4* __restrict__ x4, ushort4* __restrict__ xh4,
                            const float4* __restrict__ lB4, ushort4* __restrict__ lBh4) {
  const int stride = gridDim.x * blockDim.x;
  const int t0 = blockIdx.x * blockDim.x + threadIdx.x;
  for (int d = t0; d < OUTF * INF / 8; d += stride) {
    int4 a = qc4[2 * d];
    int4 b = qc4[2 * d + 1];
    pk[d] = (uint)(a.x & 15) | ((uint)(a.y & 15) << 4) | ((uint)(a.z & 15) << 8) |
            ((uint)(a.w & 15) << 12) | ((uint)(b.x & 15) << 16) | ((uint)(b.y & 15) << 20) |
            ((uint)(b.z & 15) << 24) | ((uint)(b.w & 15) << 28);
  }
  for (int i = t0; i < TOK * INF / 4; i += stride) {
    float4 v = x4[i];
    ushort4 o;
    o.x = f2h(v.x); o.y = f2h(v.y); o.z = f2h(v.z); o.w = f2h(v.w);
    xh4[i] = o;
  }
  for (int i = t0; i < OUTF * 16; i += stride) {
    int n = i >> 4, jq = i & 15;
    ushort4 o = {0, 0, 0, 0};
    if (jq < 4) {
      float4 v = lB4[n * 4 + jq];
      o.x = f2h(v.x); o.y = f2h(v.y); o.z = f2h(v.z); o.w = f2h(v.w);
    }
    lBh4[i] = o;
  }
}

// kernel 2: xa2[m][j] = f16( 2 * sum_k x[m][k]*lora_A[j][k] ), [TOK,64] zero-padded
__global__ __launch_bounds__(1024)
void xa_kernel(const float* __restrict__ x, const float* __restrict__ lA,
               ushort* __restrict__ xa2) {
  const int m = blockIdx.x;
  const int t = threadIdx.x;
  const float4* x4 = (const float4*)(x + (size_t)m * INF);
  const float4* lA4 = (const float4*)lA;
  float4 xv = x4[t];
  float acc[16];
#pragma unroll
  for (int j = 0; j < 16; ++j) {
    float4 a = lA4[j * (INF / 4) + t];
    acc[j] = xv.x * a.x + xv.y * a.y + xv.z * a.z + xv.w * a.w;
  }
#pragma unroll
  for (int j = 0; j < 16; ++j)
#pragma unroll
    for (int s = 32; s > 0; s >>= 1) acc[j] += __shfl_xor(acc[j], s, 64);
  __shared__ float red[16][16];
  const int w = t >> 6, l = t & 63;
  if (l == 0) {
#pragma unroll
    for (int j = 0; j < 16; ++j) red[w][j] = acc[j];
  }
  __syncthreads();
  if (t < 64) {
    ushort v = 0;
    if (t < 16) {
      float s = 0.f;
#pragma unroll
      for (int w2 = 0; w2 < 16; ++w2) s += red[w2][t];
      v = f2h(2.0f * s);
    }
    xa2[m * 64 + t] = v;
  }
}

// kernel 3: K-split fused dequant GEMM, R5 structure with slack-scheduled loads:
// every VMEM load is issued a full compute-phase before the barrier that drains it.
__global__ __launch_bounds__(256, 3)
void gemm_kernel(const uint* __restrict__ pk, const float* __restrict__ am,
                 const ushort* __restrict__ xh, const ushort* __restrict__ lBh,
                 const ushort* __restrict__ xa2, float* __restrict__ dest, int nst) {
  __shared__ ushort Abuf[BM * 64];  // 32 KB, chunk-swizzled
  __shared__ __half2 tbl[256];      // byte -> (nf4[lo], nf4[hi]) unscaled

  const int tid = threadIdx.x;
  const int w = tid >> 6;
  const int l = tid & 63;
  const int chunk = l >> 4;  // 0..3
  const int rlo = l & 15;
  const int split = blockIdx.x / NT2;
  const int ntile = blockIdx.x - split * NT2;
  const int n0 = ntile * BN;
  const int k0 = split * nst * 64;

  tbl[tid & 255] = __halves2half2(__float2half(NF4_TBL[tid & 15]),
                                  __float2half(NF4_TBL[(tid >> 4) & 15]));

  // A deposit geometry (verified R3/R5): issue i covers rows i*32 + w*8 + l/8
  const int arow = w * 8 + (l >> 3);
  const int acol = ((l & 7) ^ (l >> 3)) << 3;

  int aoff[2][4];
#pragma unroll
  for (int ks2 = 0; ks2 < 2; ++ks2) {
    const int cc = ks2 * 4 + chunk;
#pragma unroll
    for (int mt = 0; mt < 4; ++mt)
      aoff[ks2][mt] = (w * 64 + mt * 16 + rlo) * 64 + ((cc ^ (l & 7)) << 3);
  }

  int col[4];
  const char* qp[4];
  const float* amp[4];
#pragma unroll
  for (int nt = 0; nt < 4; ++nt) {
    col[nt] = n0 + nt * 16 + rlo;
    qp[nt] = (const char*)pk + (size_t)col[nt] * (INF / 2) + (k0 >> 1) + chunk * 4;
    amp[nt] = am + (size_t)col[nt] * 64 + (k0 >> 6);
  }

  f32x4 acc[4][4];
#pragma unroll
  for (int mt = 0; mt < 4; ++mt)
#pragma unroll
    for (int nt = 0; nt < 4; ++nt) acc[mt][nt] = (f32x4){0.f, 0.f, 0.f, 0.f};

  // prologue: issue A(0) asyncs + load q(0)/amax(0) into stage 0
#pragma unroll
  for (int i = 0; i < 8; ++i) {
    const ushort* g = xh + (size_t)(i * 32 + arow) * INF + k0 + acol;
    async_cp16(g, &Abuf[(i * 256 + w * 64) * 8]);
  }
  uint qd[2][8];
  float ax[2][4];
#pragma unroll
  for (int nt = 0; nt < 4; ++nt) {
    qd[0][nt * 2 + 0] = *(const uint*)(qp[nt]);
    qd[0][nt * 2 + 1] = *(const uint*)(qp[nt] + 16);
    ax[0][nt] = amp[nt][0];
  }

#pragma unroll 2
  for (int s = 0; s < nst; ++s) {
    const int p = s & 1;
    __syncthreads();  // barrier A: drains A(s) asyncs + q(s) loads (both have full slack)

    // pull this step's A frags to registers (lgkm only)
    f16x8 areg[2][4];
#pragma unroll
    for (int ks2 = 0; ks2 < 2; ++ks2)
#pragma unroll
      for (int mt = 0; mt < 4; ++mt) areg[ks2][mt] = *(const f16x8*)&Abuf[aoff[ks2][mt]];

    __syncthreads();  // barrier B: cheap (no VMEM in flight); Abuf now free

    // issue next step's loads — they drain at barrier A(s+1), after the compute below
    if (s + 1 < nst) {
      const int kb = k0 + (s + 1) * 64;
#pragma unroll
      for (int i = 0; i < 8; ++i) {
        const ushort* g = xh + (size_t)(i * 32 + arow) * INF + kb + acol;
        async_cp16(g, &Abuf[(i * 256 + w * 64) * 8]);
      }
    }
    const int sq = (s + 1 < nst) ? (s + 1) : (nst - 1);  // uniform clamp, always in-bounds
#pragma unroll
    for (int nt = 0; nt < 4; ++nt) {
      qd[p ^ 1][nt * 2 + 0] = *(const uint*)(qp[nt] + sq * 32);
      qd[p ^ 1][nt * 2 + 1] = *(const uint*)(qp[nt] + sq * 32 + 16);
      ax[p ^ 1][nt] = amp[nt][sq];
    }

    // compute step s from registers
#pragma unroll
    for (int ks2 = 0; ks2 < 2; ++ks2) {
      f16x8 b[4];
#pragma unroll
      for (int nt = 0; nt < 4; ++nt) {
        uint dw = qd[p][nt * 2 + ks2];
        __half2 ax2 = __float2half2_rn(ax[p][nt]);
        union { __half2 h[4]; f16x8 v; } u;
        u.h[0] = __hmul2(tbl[dw & 255], ax2);
        u.h[1] = __hmul2(tbl[(dw >> 8) & 255], ax2);
        u.h[2] = __hmul2(tbl[(dw >> 16) & 255], ax2);
        u.h[3] = __hmul2(tbl[dw >> 24], ax2);
        b[nt] = u.v;
      }
#pragma unroll
      for (int mt = 0; mt < 4; ++mt)
#pragma unroll
        for (int nt = 0; nt < 4; ++nt)
          acc[mt][nt] = __builtin_amdgcn_mfma_f32_16x16x32_f16(areg[ks2][mt], b[nt], acc[mt][nt], 0, 0, 0);
    }
  }

  if (split == 0) {
    // lora K-extension: k in [0,32) (rank 16 + zero pad); direct register frags
    f16x8 a_l[4], b_l[4];
#pragma unroll
    for (int mt = 0; mt < 4; ++mt)
      a_l[mt] = *(const f16x8*)(xa2 + (size_t)(w * 64 + mt * 16 + rlo) * 64 + chunk * 8);
#pragma unroll
    for (int nt = 0; nt < 4; ++nt)
      b_l[nt] = *(const f16x8*)(lBh + (size_t)col[nt] * 64 + chunk * 8);
#pragma unroll
    for (int mt = 0; mt < 4; ++mt)
#pragma unroll
      for (int nt = 0; nt < 4; ++nt)
        acc[mt][nt] = __builtin_amdgcn_mfma_f32_16x16x32_f16(a_l[mt], b_l[nt], acc[mt][nt], 0, 0, 0);
  }

  // epilogue: C/D layout col=lane&15, row=(lane>>4)*4+reg; each split owns a slice
  float* dst = dest + (size_t)split * TOK * OUTF;
#pragma unroll
  for (int mt = 0; mt < 4; ++mt) {
#pragma unroll
    for (int nt = 0; nt < 4; ++nt) {
      int c = col[nt];
#pragma unroll
      for (int r = 0; r < 4; ++r) {
        int row = w * 64 + mt * 16 + chunk * 4 + r;
        dst[(size_t)row * OUTF + c] = acc[mt][nt][r];
      }
    }
  }
}

// kernel 4: sum K-split partials -> out
__global__ void reduce_kernel(const float4* __restrict__ part, float4* __restrict__ out,
                              int ks) {
  const int QN = TOK * OUTF / 4;
  int i = blockIdx.x * blockDim.x + threadIdx.x;
  if (i < QN) {
    float4 s = part[i];
    for (int s2 = 1; s2 < ks; ++s2) {
      float4 p = part[(size_t)s2 * QN + i];
      s.x += p.x; s.y += p.y; s.z += p.z; s.w += p.w;
    }
    out[i] = s;
  }
}

extern "C" void kernel_launch(void* const* d_in, const int* in_sizes, int n_in,
                              void* d_out, int out_size, void* d_ws, size_t ws_size,
                              hipStream_t stream) {
  const float* x = (const float*)d_in[0];
  const int* qc = (const int*)d_in[1];
  const float* am = (const float*)d_in[2];
  const float* lA = (const float*)d_in[3];
  const float* lB = (const float*)d_in[4];
  float* out = (float*)d_out;

  const size_t off_lB = (size_t)TOK * INF * 2;             // 2.10 MB
  const size_t off_xa2 = off_lB + (size_t)OUTF * 64 * 2;   // +1.41 MB
  const size_t off_pk = off_xa2 + (size_t)TOK * 64 * 2;    // +32 KB  = 3,538,944
  const size_t off_part = off_pk + (size_t)OUTF * INF / 2; // +22.5 MB = 26,083,328
  const size_t part_bytes = (size_t)TOK * OUTF * 4;        // 11.27 MB per split

  ushort* xh = (ushort*)d_ws;
  ushort* lBh = (ushort*)((char*)d_ws + off_lB);
  ushort* xa2 = (ushort*)((char*)d_ws + off_xa2);
  uint* pk = (uint*)((char*)d_ws + off_pk);
  float* part = (float*)((char*)d_ws + off_part);

  int ks = 1;
  if (ws_size >= off_part + 8 * part_bytes) ks = 8;        // ws ~688 MB observed -> ks=8
  else if (ws_size >= off_part + 4 * part_bytes) ks = 4;
  else if (ws_size >= off_part + 2 * part_bytes) ks = 2;
  float* dest = (ks == 1) ? out : part;

  prep_kernel<<<4096, 256, 0, stream>>>((const int4*)qc, pk, (const float4*)x,
                                        (ushort4*)xh, (const float4*)lB, (ushort4*)lBh);
  xa_kernel<<<TOK, 1024, 0, stream>>>(x, lA, xa2);
  gemm_kernel<<<NT2 * ks, 256, 0, stream>>>(pk, am, xh, lBh, xa2, dest, 64 / ks);
  if (ks > 1)
    reduce_kernel<<<(TOK * OUTF / 4 + 255) / 256, 256, 0, stream>>>((const float4*)part,
                                                                    (float4*)out, ks);
}

// Round 8
// 314.078 us; speedup vs baseline: 1.3856x; 1.2306x over previous
//
#include <hip/hip_runtime.h>
#include <hip/hip_fp16.h>

typedef unsigned int uint;
typedef unsigned short ushort;

typedef __attribute__((ext_vector_type(8))) _Float16 f16x8;
typedef __attribute__((ext_vector_type(4))) float f32x4;

#define TOK 256
#define OUTF 11008
#define INF 4096
#define BM 256
#define BN 64
#define NT2 172  // OUTF / BN

__device__ __constant__ float NF4_TBL[16] = {
    -1.0f, -0.6961928009986877f, -0.5250730514526367f, -0.39491748809814453f,
    -0.28444138169288635f, -0.18477343022823334f, -0.09105003625154495f, 0.0f,
    0.07958029955625534f, 0.16093020141124725f, 0.24611230194568634f,
    0.33791524171829224f, 0.44070982933044434f, 0.5626170039176941f,
    0.7229568362236023f, 1.0f};

__device__ __forceinline__ ushort f2h(float f) {
  return __half_as_ushort(__float2half(f));
}

// async global->LDS, 16B per lane; lds base wave-uniform + lane*16 (global addr per-lane)
__device__ __forceinline__ void async_cp16(const void* g, void* l) {
  __builtin_amdgcn_global_load_lds(
      (const __attribute__((address_space(1))) uint*)g,
      (__attribute__((address_space(3))) uint*)l, 16, 0, 0);
}

// kernel 1 (prep, R5-proven): pack q int32->nibbles row-major; x fp32->f16;
// lora_B fp32 [OUTF,16] -> f16 [OUTF,64] zero-padded
__global__ void prep_kernel(const int4* __restrict__ qc4, uint* __restrict__ pk,
                            const float4* __restrict__ x4, ushort4* __restrict__ xh4,
                            const float4* __restrict__ lB4, ushort4* __restrict__ lBh4) {
  const int stride = gridDim.x * blockDim.x;
  const int t0 = blockIdx.x * blockDim.x + threadIdx.x;
  for (int d = t0; d < OUTF * INF / 8; d += stride) {
    int4 a = qc4[2 * d];
    int4 b = qc4[2 * d + 1];
    pk[d] = (uint)(a.x & 15) | ((uint)(a.y & 15) << 4) | ((uint)(a.z & 15) << 8) |
            ((uint)(a.w & 15) << 12) | ((uint)(b.x & 15) << 16) | ((uint)(b.y & 15) << 20) |
            ((uint)(b.z & 15) << 24) | ((uint)(b.w & 15) << 28);
  }
  for (int i = t0; i < TOK * INF / 4; i += stride) {
    float4 v = x4[i];
    ushort4 o;
    o.x = f2h(v.x); o.y = f2h(v.y); o.z = f2h(v.z); o.w = f2h(v.w);
    xh4[i] = o;
  }
  for (int i = t0; i < OUTF * 16; i += stride) {
    int n = i >> 4, jq = i & 15;
    ushort4 o = {0, 0, 0, 0};
    if (jq < 4) {
      float4 v = lB4[n * 4 + jq];
      o.x = f2h(v.x); o.y = f2h(v.y); o.z = f2h(v.z); o.w = f2h(v.w);
    }
    lBh4[i] = o;
  }
}

// kernel 2: xa2[m][j] = f16( 2 * sum_k x[m][k]*lora_A[j][k] ), [TOK,64] zero-padded
__global__ __launch_bounds__(1024)
void xa_kernel(const float* __restrict__ x, const float* __restrict__ lA,
               ushort* __restrict__ xa2) {
  const int m = blockIdx.x;
  const int t = threadIdx.x;
  const float4* x4 = (const float4*)(x + (size_t)m * INF);
  const float4* lA4 = (const float4*)lA;
  float4 xv = x4[t];
  float acc[16];
#pragma unroll
  for (int j = 0; j < 16; ++j) {
    float4 a = lA4[j * (INF / 4) + t];
    acc[j] = xv.x * a.x + xv.y * a.y + xv.z * a.z + xv.w * a.w;
  }
#pragma unroll
  for (int j = 0; j < 16; ++j)
#pragma unroll
    for (int s = 32; s > 0; s >>= 1) acc[j] += __shfl_xor(acc[j], s, 64);
  __shared__ float red[16][16];
  const int w = t >> 6, l = t & 63;
  if (l == 0) {
#pragma unroll
    for (int j = 0; j < 16; ++j) red[w][j] = acc[j];
  }
  __syncthreads();
  if (t < 64) {
    ushort v = 0;
    if (t < 16) {
      float s = 0.f;
#pragma unroll
      for (int w2 = 0; w2 < 16; ++w2) s += red[w2][t];
      v = f2h(2.0f * s);
    }
    xa2[m * 64 + t] = v;
  }
}

// kernel 3: K-split fused dequant GEMM. ALL q/amax traffic enters via coalesced
// global_load_lds; cooperative dequant (2 dwords/thread) into swizzled Bbuf.
__global__ __launch_bounds__(256, 3)
void gemm_kernel(const uint* __restrict__ pk, const float* __restrict__ am,
                 const ushort* __restrict__ xh, const ushort* __restrict__ lBh,
                 const ushort* __restrict__ xa2, float* __restrict__ dest, int nst) {
  __shared__ ushort Abuf[BM * 64];  // 32 KB, octet-swizzled (proven R3/R5/R7)
  __shared__ ushort Bbuf[64 * 64];  // 8 KB, octet-swizzled
  __shared__ uint Qbuf[512];        // 2 KB: this step's codes, [2 halves][64 rows][16B]
  __shared__ float Qax[1024];       // 4 KB: 16 k-blocks of amax, [j4][64 rows][4]
  __shared__ __half2 tbl[256];      // byte -> (nf4[lo], nf4[hi]) unscaled

  const int tid = threadIdx.x;
  const int w = tid >> 6;
  const int l = tid & 63;
  const int chunk = l >> 4;  // 0..3
  const int rlo = l & 15;
  const int split = blockIdx.x / NT2;
  const int ntile = blockIdx.x - split * NT2;
  const int n0 = ntile * BN;
  const int kb0 = split * nst;  // in 64-k blocks

  tbl[tid & 255] = __halves2half2(__float2half(NF4_TBL[tid & 15]),
                                  __float2half(NF4_TBL[(tid >> 4) & 15]));

  // A staging geometry (verified R3/R5/R7)
  const int arow = w * 8 + (l >> 3);
  const int acol = ((l & 7) ^ (l >> 3)) << 3;
  int aoff[2][4];
#pragma unroll
  for (int ks2 = 0; ks2 < 2; ++ks2) {
    const int cc = ks2 * 4 + chunk;
#pragma unroll
    for (int mt = 0; mt < 4; ++mt)
      aoff[ks2][mt] = (w * 64 + mt * 16 + rlo) * 64 + ((cc ^ (l & 7)) << 3);
  }

  // cooperative dequant mapping: thread -> (row dr, octets w and w+4)
  const int dr = tid & 63;
  const int p7 = dr & 7;
  const int bw0 = dr * 64 + ((w ^ p7) << 3);
  const int bw1 = dr * 64 + (((w + 4) ^ p7) << 3);

  // b-frag LDS read offsets (swizzle-matched; rr&7 == rlo&7)
  int boff[2][4];
#pragma unroll
  for (int ks2 = 0; ks2 < 2; ++ks2)
#pragma unroll
    for (int nt = 0; nt < 4; ++nt)
      boff[ks2][nt] = (nt * 16 + rlo) * 64 + (((ks2 * 4 + chunk) ^ (rlo & 7)) << 3);

  f32x4 acc[4][4];
#pragma unroll
  for (int mt = 0; mt < 4; ++mt)
#pragma unroll
    for (int nt = 0; nt < 4; ++nt) acc[mt][nt] = (f32x4){0.f, 0.f, 0.f, 0.f};

  // prologue staging (all coalesced asyncs)
  if (w == 0) {
#pragma unroll
    for (int j = 0; j < 4; ++j)  // amax group 0: 16 k-blocks
      async_cp16(am + (size_t)(n0 + l) * 64 + kb0 + j * 4, (char*)Qax + j * 1024);
#pragma unroll
    for (int j = 0; j < 2; ++j)  // q codes for step 0
      async_cp16((const char*)pk + (size_t)(n0 + l) * 2048 + kb0 * 32 + j * 16,
                 (char*)Qbuf + j * 1024);
  }
#pragma unroll
  for (int i = 0; i < 8; ++i) {
    const ushort* g = xh + (size_t)(i * 32 + arow) * INF + kb0 * 64 + acol;
    async_cp16(g, &Abuf[(i * 256 + w * 64) * 8]);
  }

  for (int s = 0; s < nst; ++s) {
    __syncthreads();  // barrier A: drains step-s staging (issued a full phase ago)

    // cooperative dequant: 2 dwords/thread -> Bbuf
    uint q0 = Qbuf[dr * 4 + w];
    uint q1 = Qbuf[256 + dr * 4 + w];
    const int sl = s & 15;
    __half2 ax2 = __float2half2_rn(Qax[(sl >> 2) * 256 + dr * 4 + (sl & 3)]);
    {
      union { __half2 h[4]; f16x8 v; } u;
      u.h[0] = __hmul2(tbl[q0 & 255], ax2);
      u.h[1] = __hmul2(tbl[(q0 >> 8) & 255], ax2);
      u.h[2] = __hmul2(tbl[(q0 >> 16) & 255], ax2);
      u.h[3] = __hmul2(tbl[q0 >> 24], ax2);
      *(f16x8*)&Bbuf[bw0] = u.v;
    }
    {
      union { __half2 h[4]; f16x8 v; } u;
      u.h[0] = __hmul2(tbl[q1 & 255], ax2);
      u.h[1] = __hmul2(tbl[(q1 >> 8) & 255], ax2);
      u.h[2] = __hmul2(tbl[(q1 >> 16) & 255], ax2);
      u.h[3] = __hmul2(tbl[q1 >> 24], ax2);
      *(f16x8*)&Bbuf[bw1] = u.v;
    }
    // A frags to registers
    f16x8 areg[2][4];
#pragma unroll
    for (int ks2 = 0; ks2 < 2; ++ks2)
#pragma unroll
      for (int mt = 0; mt < 4; ++mt) areg[ks2][mt] = *(const f16x8*)&Abuf[aoff[ks2][mt]];

    __syncthreads();  // barrier B: Bbuf ready, Abuf/Qbuf consumed

    // issue step-(s+1) staging — full MFMA phase of slack before its drain
    if (s + 1 < nst) {
      const int kb = kb0 + s + 1;
#pragma unroll
      for (int i = 0; i < 8; ++i) {
        const ushort* g = xh + (size_t)(i * 32 + arow) * INF + kb * 64 + acol;
        async_cp16(g, &Abuf[(i * 256 + w * 64) * 8]);
      }
      if (w == 0) {
#pragma unroll
        for (int j = 0; j < 2; ++j)
          async_cp16((const char*)pk + (size_t)(n0 + l) * 2048 + kb * 32 + j * 16,
                     (char*)Qbuf + j * 1024);
        if (((s + 1) & 15) == 0) {  // next amax group of 16 k-blocks
#pragma unroll
          for (int j = 0; j < 4; ++j)
            async_cp16(am + (size_t)(n0 + l) * 64 + kb + j * 4, (char*)Qax + j * 1024);
        }
      }
    }

    // compute: b-frags from Bbuf + 32 MFMAs
#pragma unroll
    for (int ks2 = 0; ks2 < 2; ++ks2) {
      f16x8 b[4];
#pragma unroll
      for (int nt = 0; nt < 4; ++nt) b[nt] = *(const f16x8*)&Bbuf[boff[ks2][nt]];
#pragma unroll
      for (int mt = 0; mt < 4; ++mt)
#pragma unroll
        for (int nt = 0; nt < 4; ++nt)
          acc[mt][nt] = __builtin_amdgcn_mfma_f32_16x16x32_f16(areg[ks2][mt], b[nt], acc[mt][nt], 0, 0, 0);
    }
  }

  if (split == 0) {
    // lora K-extension: k in [0,32) (rank 16 + zero pad); direct register frags
    f16x8 a_l[4], b_l[4];
#pragma unroll
    for (int mt = 0; mt < 4; ++mt)
      a_l[mt] = *(const f16x8*)(xa2 + (size_t)(w * 64 + mt * 16 + rlo) * 64 + chunk * 8);
#pragma unroll
    for (int nt = 0; nt < 4; ++nt)
      b_l[nt] = *(const f16x8*)(lBh + (size_t)(n0 + nt * 16 + rlo) * 64 + chunk * 8);
#pragma unroll
    for (int mt = 0; mt < 4; ++mt)
#pragma unroll
      for (int nt = 0; nt < 4; ++nt)
        acc[mt][nt] = __builtin_amdgcn_mfma_f32_16x16x32_f16(a_l[mt], b_l[nt], acc[mt][nt], 0, 0, 0);
  }

  // epilogue: C/D layout col=lane&15, row=(lane>>4)*4+reg; each split owns a slice
  float* dst = dest + (size_t)split * TOK * OUTF;
#pragma unroll
  for (int mt = 0; mt < 4; ++mt) {
#pragma unroll
    for (int nt = 0; nt < 4; ++nt) {
      int c = n0 + nt * 16 + rlo;
#pragma unroll
      for (int r = 0; r < 4; ++r) {
        int row = w * 64 + mt * 16 + chunk * 4 + r;
        dst[(size_t)row * OUTF + c] = acc[mt][nt][r];
      }
    }
  }
}

// kernel 4: sum K-split partials -> out
__global__ void reduce_kernel(const float4* __restrict__ part, float4* __restrict__ out,
                              int ks) {
  const int QN = TOK * OUTF / 4;
  int i = blockIdx.x * blockDim.x + threadIdx.x;
  if (i < QN) {
    float4 s = part[i];
    for (int s2 = 1; s2 < ks; ++s2) {
      float4 p = part[(size_t)s2 * QN + i];
      s.x += p.x; s.y += p.y; s.z += p.z; s.w += p.w;
    }
    out[i] = s;
  }
}

extern "C" void kernel_launch(void* const* d_in, const int* in_sizes, int n_in,
                              void* d_out, int out_size, void* d_ws, size_t ws_size,
                              hipStream_t stream) {
  const float* x = (const float*)d_in[0];
  const int* qc = (const int*)d_in[1];
  const float* am = (const float*)d_in[2];
  const float* lA = (const float*)d_in[3];
  const float* lB = (const float*)d_in[4];
  float* out = (float*)d_out;

  const size_t off_lB = (size_t)TOK * INF * 2;             // 2.10 MB
  const size_t off_xa2 = off_lB + (size_t)OUTF * 64 * 2;   // +1.41 MB
  const size_t off_pk = off_xa2 + (size_t)TOK * 64 * 2;    // +32 KB  = 3,538,944
  const size_t off_part = off_pk + (size_t)OUTF * INF / 2; // +22.5 MB = 26,083,328
  const size_t part_bytes = (size_t)TOK * OUTF * 4;        // 11.27 MB per split

  ushort* xh = (ushort*)d_ws;
  ushort* lBh = (ushort*)((char*)d_ws + off_lB);
  ushort* xa2 = (ushort*)((char*)d_ws + off_xa2);
  uint* pk = (uint*)((char*)d_ws + off_pk);
  float* part = (float*)((char*)d_ws + off_part);

  int ks = 1;  // nst must stay a multiple of 16 (Qax grouping): ks in {1,2,4}
  if (ws_size >= off_part + 4 * part_bytes) ks = 4;  // ws ~688 MB observed -> ks=4
  else if (ws_size >= off_part + 2 * part_bytes) ks = 2;
  float* dest = (ks == 1) ? out : part;

  prep_kernel<<<4096, 256, 0, stream>>>((const int4*)qc, pk, (const float4*)x,
                                        (ushort4*)xh, (const float4*)lB, (ushort4*)lBh);
  xa_kernel<<<TOK, 1024, 0, stream>>>(x, lA, xa2);
  gemm_kernel<<<NT2 * ks, 256, 0, stream>>>(pk, am, xh, lBh, xa2, dest, 64 / ks);
  if (ks > 1)
    reduce_kernel<<<(TOK * OUTF / 4 + 255) / 256, 256, 0, stream>>>((const float4*)part,
                                                                    (float4*)out, ks);
}

// Round 9
// 309.422 us; speedup vs baseline: 1.4064x; 1.0150x over previous
//
#include <hip/hip_runtime.h>
#include <hip/hip_fp16.h>

typedef unsigned int uint;
typedef unsigned short ushort;

typedef __attribute__((ext_vector_type(8))) _Float16 f16x8;
typedef __attribute__((ext_vector_type(4))) float f32x4;

#define TOK 256
#define OUTF 11008
#define INF 4096
#define BM 256
#define BN 64
#define NT2 172  // OUTF / BN

__device__ __constant__ float NF4_TBL[16] = {
    -1.0f, -0.6961928009986877f, -0.5250730514526367f, -0.39491748809814453f,
    -0.28444138169288635f, -0.18477343022823334f, -0.09105003625154495f, 0.0f,
    0.07958029955625534f, 0.16093020141124725f, 0.24611230194568634f,
    0.33791524171829224f, 0.44070982933044434f, 0.5626170039176941f,
    0.7229568362236023f, 1.0f};

__device__ __forceinline__ ushort f2h(float f) {
  return __half_as_ushort(__float2half(f));
}

// async global->LDS, 16B per lane; lds base wave-uniform + lane*16
__device__ __forceinline__ void async_cp16(const void* g, void* l) {
  __builtin_amdgcn_global_load_lds(
      (const __attribute__((address_space(1))) uint*)g,
      (__attribute__((address_space(3))) uint*)l, 16, 0, 0);
}

// table value via VGPR crossbar (conflict-free); lanes 0..15 of every 16 hold the table
__device__ __forceinline__ float nf4v(int c, int tbits) {
  return __int_as_float(__builtin_amdgcn_ds_bpermute(c << 2, tbits));
}

// 4 raw codes -> 4 scaled halfs (8B)
__device__ __forceinline__ uint2 dq4(int4 c, __half2 ax2, int tbits) {
  __half2 h0 = __floats2half2_rn(nf4v(c.x, tbits), nf4v(c.y, tbits));
  __half2 h1 = __floats2half2_rn(nf4v(c.z, tbits), nf4v(c.w, tbits));
  h0 = __hmul2(h0, ax2);
  h1 = __hmul2(h1, ax2);
  union { __half2 h[2]; uint2 u; } r;
  r.h[0] = h0; r.h[1] = h1;
  return r.u;
}

// kernel 1: x fp32 -> f16 (float4); lora_B fp32 [OUTF,16] -> f16 [OUTF,64] zero-padded
__global__ void prep_kernel(const float4* __restrict__ x4, ushort4* __restrict__ xh4,
                            const float4* __restrict__ lB4, ushort4* __restrict__ lBh4) {
  const int stride = gridDim.x * blockDim.x;
  const int t0 = blockIdx.x * blockDim.x + threadIdx.x;
  for (int i = t0; i < TOK * INF / 4; i += stride) {
    float4 v = x4[i];
    ushort4 o;
    o.x = f2h(v.x); o.y = f2h(v.y); o.z = f2h(v.z); o.w = f2h(v.w);
    xh4[i] = o;
  }
  for (int i = t0; i < OUTF * 16; i += stride) {
    int n = i >> 4, jq = i & 15;
    ushort4 o = {0, 0, 0, 0};
    if (jq < 4) {
      float4 v = lB4[n * 4 + jq];
      o.x = f2h(v.x); o.y = f2h(v.y); o.z = f2h(v.z); o.w = f2h(v.w);
    }
    lBh4[i] = o;
  }
}

// kernel 2: xa2[m][j] = f16( 2 * sum_k x[m][k]*lora_A[j][k] ), [TOK,64] zero-padded
__global__ __launch_bounds__(1024)
void xa_kernel(const float* __restrict__ x, const float* __restrict__ lA,
               ushort* __restrict__ xa2) {
  const int m = blockIdx.x;
  const int t = threadIdx.x;
  const float4* x4 = (const float4*)(x + (size_t)m * INF);
  const float4* lA4 = (const float4*)lA;
  float4 xv = x4[t];
  float acc[16];
#pragma unroll
  for (int j = 0; j < 16; ++j) {
    float4 a = lA4[j * (INF / 4) + t];
    acc[j] = xv.x * a.x + xv.y * a.y + xv.z * a.z + xv.w * a.w;
  }
#pragma unroll
  for (int j = 0; j < 16; ++j)
#pragma unroll
    for (int s = 32; s > 0; s >>= 1) acc[j] += __shfl_xor(acc[j], s, 64);
  __shared__ float red[16][16];
  const int w = t >> 6, l = t & 63;
  if (l == 0) {
#pragma unroll
    for (int j = 0; j < 16; ++j) red[w][j] = acc[j];
  }
  __syncthreads();
  if (t < 64) {
    ushort v = 0;
    if (t < 16) {
      float s = 0.f;
#pragma unroll
      for (int w2 = 0; w2 < 16; ++w2) s += red[w2][t];
      v = f2h(2.0f * s);
    }
    xa2[m * 64 + t] = v;
  }
}

// kernel 3: single-pass fused dequant GEMM — raw q codes read coalesced into
// registers in the slack slot, bpermute dequant (no LDS table), swizzled Bbuf.
__global__ __launch_bounds__(256, 3)
void gemm_kernel(const int* __restrict__ qc, const float* __restrict__ am,
                 const ushort* __restrict__ xh, const ushort* __restrict__ lBh,
                 const ushort* __restrict__ xa2, float* __restrict__ dest, int nst) {
  __shared__ ushort Abuf[BM * 64];  // 32 KB, octet-swizzled (proven R3..R8)
  __shared__ ushort Bbuf[64 * 64];  // 8 KB, octet-swizzled
  __shared__ float Qax[1024];       // 4 KB: 16 k-blocks of amax, [j4][64 rows][4]

  const int tid = threadIdx.x;
  const int w = tid >> 6;
  const int l = tid & 63;
  const int chunk = l >> 4;  // 0..3
  const int rlo = l & 15;
  const int split = blockIdx.x / NT2;
  const int ntile = blockIdx.x - split * NT2;
  const int n0 = ntile * BN;
  const int kb0 = split * nst;  // in 64-k blocks

  const int tbits = __float_as_int(NF4_TBL[l & 15]);

  // A staging geometry (verified R3/R5/R7/R8)
  const int arow = w * 8 + (l >> 3);
  const int acol = ((l & 7) ^ (l >> 3)) << 3;
  int aoff[2][4];
#pragma unroll
  for (int ks2 = 0; ks2 < 2; ++ks2) {
    const int cc = ks2 * 4 + chunk;
#pragma unroll
    for (int mt = 0; mt < 4; ++mt)
      aoff[ks2][mt] = (w * 64 + mt * 16 + rlo) * 64 + ((cc ^ (l & 7)) << 3);
  }

  // q-load geometry (coalesced): per pass p, row = p*16 + (tid>>4), chunk ch = tid&15
  const int qrg = tid >> 4;  // 0..15
  const int qch = tid & 15;  // 0..15
  const int* qbase[4];
  int bdst[4];
#pragma unroll
  for (int p = 0; p < 4; ++p) {
    int r = p * 16 + qrg;
    qbase[p] = qc + (size_t)(n0 + r) * INF + kb0 * 64 + qch * 4;
    bdst[p] = r * 64 + (((qch >> 1) ^ (r & 7)) << 3) + (qch & 1) * 4;
  }

  // b-frag LDS read offsets (swizzle-matched)
  int boff[2][4];
#pragma unroll
  for (int ks2 = 0; ks2 < 2; ++ks2)
#pragma unroll
    for (int nt = 0; nt < 4; ++nt)
      boff[ks2][nt] = (nt * 16 + rlo) * 64 + (((ks2 * 4 + chunk) ^ (rlo & 7)) << 3);

  f32x4 acc[4][4];
#pragma unroll
  for (int mt = 0; mt < 4; ++mt)
#pragma unroll
    for (int nt = 0; nt < 4; ++nt) acc[mt][nt] = (f32x4){0.f, 0.f, 0.f, 0.f};

  // prologue: A(0) DMA, Qax group 0 DMA, q(0) register loads
  if (w == 0) {
#pragma unroll
    for (int j = 0; j < 4; ++j)
      async_cp16(am + (size_t)(n0 + l) * 64 + kb0 + j * 4, (char*)Qax + j * 1024);
  }
#pragma unroll
  for (int i = 0; i < 8; ++i) {
    const ushort* g = xh + (size_t)(i * 32 + arow) * INF + kb0 * 64 + acol;
    async_cp16(g, &Abuf[(i * 256 + w * 64) * 8]);
  }
  int4 qreg[4];
#pragma unroll
  for (int p = 0; p < 4; ++p) qreg[p] = *(const int4*)(qbase[p]);

  for (int s = 0; s < nst; ++s) {
    __syncthreads();  // barrier A: drains A(s)/Qax DMA + q(s) register loads

    // dequant q(s) -> Bbuf (bpermute, conflict-free) ; amax per row from Qax
    const int sl = s & 15;
#pragma unroll
    for (int p = 0; p < 4; ++p) {
      int r = p * 16 + qrg;
      __half2 ax2 = __float2half2_rn(Qax[(sl >> 2) * 256 + r * 4 + (sl & 3)]);
      *(uint2*)&Bbuf[bdst[p]] = dq4(qreg[p], ax2, tbits);
    }
    // A frags to registers
    f16x8 areg[2][4];
#pragma unroll
    for (int ks2 = 0; ks2 < 2; ++ks2)
#pragma unroll
      for (int mt = 0; mt < 4; ++mt) areg[ks2][mt] = *(const f16x8*)&Abuf[aoff[ks2][mt]];

    __syncthreads();  // barrier B: Bbuf ready, Abuf consumed

    // slack slot: issue step-(s+1) staging (drains at barrier A(s+1), after compute)
    if (s + 1 < nst) {
      const int kb = kb0 + s + 1;
#pragma unroll
      for (int i = 0; i < 8; ++i) {
        const ushort* g = xh + (size_t)(i * 32 + arow) * INF + kb * 64 + acol;
        async_cp16(g, &Abuf[(i * 256 + w * 64) * 8]);
      }
#pragma unroll
      for (int p = 0; p < 4; ++p) qreg[p] = *(const int4*)(qbase[p] + (s + 1) * 64);
      if (((s + 1) & 15) == 0 && w == 0) {  // next amax group (only when nst>16)
#pragma unroll
        for (int j = 0; j < 4; ++j)
          async_cp16(am + (size_t)(n0 + l) * 64 + kb0 + s + 1 + j * 4, (char*)Qax + j * 1024);
      }
    }

    // compute: 32 MFMAs from registers + Bbuf
#pragma unroll
    for (int ks2 = 0; ks2 < 2; ++ks2) {
      f16x8 b[4];
#pragma unroll
      for (int nt = 0; nt < 4; ++nt) b[nt] = *(const f16x8*)&Bbuf[boff[ks2][nt]];
#pragma unroll
      for (int mt = 0; mt < 4; ++mt)
#pragma unroll
        for (int nt = 0; nt < 4; ++nt)
          acc[mt][nt] = __builtin_amdgcn_mfma_f32_16x16x32_f16(areg[ks2][mt], b[nt], acc[mt][nt], 0, 0, 0);
    }
  }

  if (split == 0) {
    // lora K-extension: k in [0,32) (rank 16 + zero pad); direct register frags
    f16x8 a_l[4], b_l[4];
#pragma unroll
    for (int mt = 0; mt < 4; ++mt)
      a_l[mt] = *(const f16x8*)(xa2 + (size_t)(w * 64 + mt * 16 + rlo) * 64 + chunk * 8);
#pragma unroll
    for (int nt = 0; nt < 4; ++nt)
      b_l[nt] = *(const f16x8*)(lBh + (size_t)(n0 + nt * 16 + rlo) * 64 + chunk * 8);
#pragma unroll
    for (int mt = 0; mt < 4; ++mt)
#pragma unroll
      for (int nt = 0; nt < 4; ++nt)
        acc[mt][nt] = __builtin_amdgcn_mfma_f32_16x16x32_f16(a_l[mt], b_l[nt], acc[mt][nt], 0, 0, 0);
  }

  // epilogue: C/D layout col=lane&15, row=(lane>>4)*4+reg; each split owns a slice
  float* dst = dest + (size_t)split * TOK * OUTF;
#pragma unroll
  for (int mt = 0; mt < 4; ++mt) {
#pragma unroll
    for (int nt = 0; nt < 4; ++nt) {
      int c = n0 + nt * 16 + rlo;
#pragma unroll
      for (int r = 0; r < 4; ++r) {
        int row = w * 64 + mt * 16 + chunk * 4 + r;
        dst[(size_t)row * OUTF + c] = acc[mt][nt][r];
      }
    }
  }
}

// kernel 4: sum K-split partials -> out
__global__ void reduce_kernel(const float4* __restrict__ part, float4* __restrict__ out,
                              int ks) {
  const int QN = TOK * OUTF / 4;
  int i = blockIdx.x * blockDim.x + threadIdx.x;
  if (i < QN) {
    float4 s = part[i];
    for (int s2 = 1; s2 < ks; ++s2) {
      float4 p = part[(size_t)s2 * QN + i];
      s.x += p.x; s.y += p.y; s.z += p.z; s.w += p.w;
    }
    out[i] = s;
  }
}

extern "C" void kernel_launch(void* const* d_in, const int* in_sizes, int n_in,
                              void* d_out, int out_size, void* d_ws, size_t ws_size,
                              hipStream_t stream) {
  const float* x = (const float*)d_in[0];
  const int* qc = (const int*)d_in[1];
  const float* am = (const float*)d_in[2];
  const float* lA = (const float*)d_in[3];
  const float* lB = (const float*)d_in[4];
  float* out = (float*)d_out;

  const size_t off_lB = (size_t)TOK * INF * 2;             // 2.10 MB
  const size_t off_xa2 = off_lB + (size_t)OUTF * 64 * 2;   // +1.41 MB
  const size_t off_part = off_xa2 + (size_t)TOK * 64 * 2;  // +32 KB = 3,538,944
  const size_t part_bytes = (size_t)TOK * OUTF * 4;        // 11.27 MB per split

  ushort* xh = (ushort*)d_ws;
  ushort* lBh = (ushort*)((char*)d_ws + off_lB);
  ushort* xa2 = (ushort*)((char*)d_ws + off_xa2);
  float* part = (float*)((char*)d_ws + off_part);

  int ks = 1;
  if (ws_size >= off_part + 4 * part_bytes) ks = 4;  // ws ~688 MB observed -> ks=4
  else if (ws_size >= off_part + 2 * part_bytes) ks = 2;
  float* dest = (ks == 1) ? out : part;

  prep_kernel<<<2048, 256, 0, stream>>>((const float4*)x, (ushort4*)xh,
                                        (const float4*)lB, (ushort4*)lBh);
  xa_kernel<<<TOK, 1024, 0, stream>>>(x, lA, xa2);
  gemm_kernel<<<NT2 * ks, 256, 0, stream>>>(qc, am, xh, lBh, xa2, dest, 64 / ks);
  if (ks > 1)
    reduce_kernel<<<(TOK * OUTF / 4 + 255) / 256, 256, 0, stream>>>((const float4*)part,
                                                                    (float4*)out, ks);
}